// Round 29
// baseline (108.573 us; speedup 1.0000x reference)
//
#include <hip/hip_runtime.h>
#include <hip/hip_bf16.h>
#include <math.h>

// Problem constants (fixed by reference): IN=512, H=4, C=32, H*C=128.
constexpr int IN_F = 512;
constexpr int NH   = 4;
constexpr int CH   = 32;
constexpr int HC   = 128;   // NH*CH
constexpr int BUCK = 512;   // dst nodes per bucket (CSR-contiguous)
constexpr int NBLK = 512;   // scatter blocks (edge chunks)
constexpr int SCH  = 2048;  // scatter sub-chunk (LDS sort granularity)

typedef short  short8 __attribute__((ext_vector_type(8)));
typedef float  f32x4  __attribute__((ext_vector_type(4)));

typedef __attribute__((address_space(3))) void as3_void;
typedef __attribute__((address_space(1))) void as1_void;
#define GLOAD_LDS16(g, l) \
    __builtin_amdgcn_global_load_lds((const as1_void*)(g), (as3_void*)(l), 16, 0, 0)

__device__ __forceinline__ unsigned short f2bf(float f) {
    unsigned u = __float_as_uint(f);
    unsigned r = (u + 0x7fff + ((u >> 16) & 1)) >> 16;   // RNE
    return (unsigned short)r;
}
__device__ __forceinline__ float bfu_lo(unsigned u) {
    return __uint_as_float(u << 16);
}
__device__ __forceinline__ float bfu_hi(unsigned u) {
    return __uint_as_float(u & 0xffff0000u);
}
__device__ __forceinline__ float sig_exp(float x) {
    return __expf(1.0f / (1.0f + __expf(-x)));
}

// ---------------------------------------------------------------------------
// LDS fragment readers.
// ---------------------------------------------------------------------------
__device__ __forceinline__ short8 frag_read(const char* tile, int row, int kb) {
    const int sw = (row & 7) << 4;
    const int b0 = row * 128 + ((kb)      ^ sw);
    const int b1 = row * 128 + ((kb + 32) ^ sw);
    ushort4 lo = *(const ushort4*)(tile + b0);
    ushort4 hi = *(const ushort4*)(tile + b1);
    short8 f;
    f[0] = (short)lo.x; f[1] = (short)lo.y; f[2] = (short)lo.z; f[3] = (short)lo.w;
    f[4] = (short)hi.x; f[5] = (short)hi.y; f[6] = (short)hi.z; f[7] = (short)hi.w;
    return f;
}

__device__ __forceinline__ short8 frag_read_a(const char* tile, int row, int jb) {
    const int sw = row & 7;
    const float4 lo = *(const float4*)(tile + row * 256 + (((jb)     ^ sw) << 4));
    const float4 hi = *(const float4*)(tile + row * 256 + (((jb + 4) ^ sw) << 4));
    __hip_bfloat162 p0 = __float22bfloat162_rn(float2{lo.x, lo.y});
    __hip_bfloat162 p1 = __float22bfloat162_rn(float2{lo.z, lo.w});
    __hip_bfloat162 p2 = __float22bfloat162_rn(float2{hi.x, hi.y});
    __hip_bfloat162 p3 = __float22bfloat162_rn(float2{hi.z, hi.w});
    unsigned u0 = *(unsigned*)&p0, u1 = *(unsigned*)&p1;
    unsigned u2 = *(unsigned*)&p2, u3 = *(unsigned*)&p3;
    short8 f;
    f[0] = (short)u0; f[1] = (short)(u0 >> 16);
    f[2] = (short)u1; f[3] = (short)(u1 >> 16);
    f[4] = (short)u2; f[5] = (short)(u2 >> 16);
    f[6] = (short)u3; f[7] = (short)(u3 >> 16);
    return f;
}

// ---------------------------------------------------------------------------
// K1: hist (blocks < NBLK) ∥ prep_w (blocks >= NBLK).
// ---------------------------------------------------------------------------
__global__ __launch_bounds__(256) void hist_prep(
        const int* __restrict__ dst, int* __restrict__ bcount,
        const float* __restrict__ W, unsigned short* __restrict__ Wt,
        int E, int N, int chunk, int nb) {
    __shared__ int lh[256];
    if (blockIdx.x < NBLK) {
        const int t = threadIdx.x;
        const int b = blockIdx.x;
        lh[t] = 0;
        __syncthreads();
        const int T = E + N;
        const int lo = b * chunk;
        const int hi = (lo + chunk < T) ? lo + chunk : T;
        for (int e = lo + t; e < hi; e += 256) {
            const int d = (e < E) ? dst[e] : (e - E);
            atomicAdd(&lh[d >> 9], 1);
        }
        __syncthreads();
        if (t < nb) bcount[t * NBLK + b] = lh[t];   // bucket-major
    } else {
        const int t = (blockIdx.x - NBLK) * 256 + threadIdx.x;
        if (t < IN_F * HC) {
            const int k = t >> 7, n = t & 127;
            Wt[(size_t)n * IN_F + k] = f2bf(W[t]);
        }
    }
}

// ---------------------------------------------------------------------------
// Pass 2: per bucket, exclusive scan over NBLK block counts (in place).
// ---------------------------------------------------------------------------
__global__ __launch_bounds__(256) void block_scan(
        int* __restrict__ bcount, int* __restrict__ btotal, int nb) {
    __shared__ int sh[256];
    const int b = blockIdx.x;
    const int t = threadIdx.x;
    const int i0 = b * NBLK + 2 * t;
    const int v0 = bcount[i0], v1 = bcount[i0 + 1];
    const int s = v0 + v1;
    sh[t] = s;
    __syncthreads();
    for (int off = 1; off < 256; off <<= 1) {
        int x = (t >= off) ? sh[t - off] : 0;
        __syncthreads();
        sh[t] += x;
        __syncthreads();
    }
    const int excl = sh[t] - s;
    bcount[i0]     = excl;
    bcount[i0 + 1] = excl + v0;
    if (t == 255) btotal[b] = sh[255];
}

// In-LDS exclusive scan of btotal (inclusive result left in sh).
__device__ __forceinline__ void scan_btotal(const int* __restrict__ btotal,
                                            int* sh, int nb, int t) {
    const int v = (t < nb) ? btotal[t] : 0;
    sh[t] = v;
    __syncthreads();
    for (int off = 1; off < 256; off <<= 1) {
        int x = (t >= off) ? sh[t - off] : 0;
        __syncthreads();
        sh[t] += x;
        __syncthreads();
    }
}

// ---------------------------------------------------------------------------
// K2: scatter (blocks < NBLK, block-local LDS counting sort -> coalesced
// emit; BUCK=512 so runs are ~17 edges = a full 64B line) ∥ gemm (BM=32).
// Pack: src(16) | dloc(9)<<16 | bucket(7)<<25.
// ---------------------------------------------------------------------------
__global__ __launch_bounds__(256) void scatter_gemm(
        const int* __restrict__ src, const int* __restrict__ dst,
        const int* __restrict__ bcount, const int* __restrict__ btotal,
        unsigned* __restrict__ tmp,
        const float* __restrict__ A, const unsigned short* __restrict__ Wt,
        unsigned short* __restrict__ C16,
        int E, int N, int chunk, int nb) {
    __shared__ __align__(16) char smem[24576];
    __shared__ int sh[256];
    __shared__ int cur[256];

    if (blockIdx.x < NBLK) {
        // ---- scatter path: block-local counting sort, coalesced emit ----
        unsigned* eload  = (unsigned*)smem;            // [SCH]
        unsigned* sorted = (unsigned*)(smem + 8192);   // [SCH]
        int* lhist = (int*)(smem + 16384);             // [256]
        int* lexcl = (int*)(smem + 16384 + 1024);      // [256]
        int* lcur  = (int*)(smem + 16384 + 2048);      // [256]

        const int t = threadIdx.x;
        const int b = blockIdx.x;
        scan_btotal(btotal, sh, nb, t);
        // per-bucket global write base for this block
        cur[t] = (t < nb) ? (sh[t] - btotal[t]) + bcount[t * NBLK + b] : 0;
        __syncthreads();

        const int T = E + N;
        const int lo0 = b * chunk;
        const int hi0 = (lo0 + chunk < T) ? lo0 + chunk : T;
        for (int base_e = lo0; base_e < hi0; base_e += SCH) {
            const int cnt_e = (hi0 - base_e < SCH) ? (hi0 - base_e) : SCH;
            // load + pack: bucket<<25 | dloc<<16 | src
            for (int i = t; i < cnt_e; i += 256) {
                const int e = base_e + i;
                const int s = (e < E) ? src[e] : (e - E);
                const int d = (e < E) ? dst[e] : (e - E);
                eload[i] = (unsigned)s | ((unsigned)(d & 511) << 16)
                                       | ((unsigned)(d >> 9) << 25);
            }
            lhist[t] = 0;
            __syncthreads();
            for (int i = t; i < cnt_e; i += 256)
                atomicAdd(&lhist[eload[i] >> 25], 1);
            __syncthreads();
            // exclusive scan of lhist
            const int v = lhist[t];
            for (int off = 1; off < 256; off <<= 1) {
                int x = (t >= off) ? lhist[t - off] : 0;
                __syncthreads();
                lhist[t] += x;
                __syncthreads();
            }
            const int excl = lhist[t] - v;
            lexcl[t] = excl;
            lcur[t]  = excl;
            __syncthreads();
            // sort into LDS by bucket
            for (int i = t; i < cnt_e; i += 256) {
                const unsigned ev = eload[i];
                const int p = atomicAdd(&lcur[ev >> 25], 1);
                sorted[p] = ev;
            }
            __syncthreads();
            // emit: consecutive i in a bucket -> consecutive global pos
            for (int i = t; i < cnt_e; i += 256) {
                const unsigned ev = sorted[i];
                const int bk = ev >> 25;
                tmp[cur[bk] + (i - lexcl[bk])] = ev & 0x01ffffffu;
            }
            __syncthreads();
            // advance per-bucket base by this sub-chunk's counts
            if (t < nb) cur[t] += lcur[t] - lexcl[t];
            __syncthreads();
        }
        return;
    }

    // ---- gemm path (BM=32) ----
    char* As = smem;           // 8 KB (f32 tile, 32 rows)
    char* Bs = smem + 8192;    // 16 KB (bf16 tile)

    const int tid  = threadIdx.x;
    const int lane = tid & 63;
    const int wave = tid >> 6;
    const int wr  = wave & 1;
    const int wcq = wave >> 1;
    const int brow = (blockIdx.x - NBLK) * 32;
    const int lr = lane & 15;
    const int lg = lane >> 4;

    f32x4 acc[4];
#pragma unroll
    for (int j = 0; j < 4; ++j)
        acc[j] = f32x4{0.f, 0.f, 0.f, 0.f};

    for (int kc = 0; kc < IN_F; kc += 64) {
        __syncthreads();
#pragma unroll
        for (int p = 0; p < 2; ++p) {
            const int c = tid + 256 * p;
            const int r = c >> 4, j = c & 15;
            int gr = brow + r;
            if (gr >= N) gr = 0;
            const float* srcp = A + (size_t)gr * IN_F + kc + ((j ^ (r & 7)) << 2);
            GLOAD_LDS16(srcp, As + wave * 1024 + p * 4096);
        }
#pragma unroll
        for (int p = 0; p < 4; ++p) {
            const int c = tid + 256 * p;
            const int n = c >> 3, j = c & 7;
            const unsigned short* srcp = Wt + (size_t)n * IN_F + kc
                                         + ((j ^ (n & 7)) << 3);
            GLOAD_LDS16(srcp, Bs + wave * 1024 + p * 4096);
        }
        __syncthreads();

#pragma unroll
        for (int ks = 0; ks < 2; ++ks) {
            const int jb = ks * 8 + lg;
            const int kb = ks * 64 + 8 * lg;
            short8 af = frag_read_a(As, wr * 16 + lr, jb);
            short8 bf[4];
#pragma unroll
            for (int ni = 0; ni < 4; ++ni)
                bf[ni] = frag_read(Bs, wcq * 64 + ni * 16 + lr, kb);
#pragma unroll
            for (int ni = 0; ni < 4; ++ni)
                acc[ni] = __builtin_amdgcn_mfma_f32_16x16x32_bf16(
                    af, bf[ni], acc[ni], 0, 0, 0);
        }
    }

    const int r0 = brow + wr * 16 + 4 * lg;
#pragma unroll
    for (int ni = 0; ni < 4; ++ni) {
        const int c0 = wcq * 64 + ni * 16 + lr;
#pragma unroll
        for (int j = 0; j < 4; ++j) {
            const int r = r0 + j;
            if (r < N) C16[(size_t)r * HC + c0] = f2bf(acc[ni][j]);
        }
    }
}

// ---------------------------------------------------------------------------
// K3: fine_scatter (blocks < nb; 512 dsts/bucket) ∥ node_logits (rest).
// ---------------------------------------------------------------------------
__global__ __launch_bounds__(256) void fine_logits(
        const int* __restrict__ btotal, const unsigned* __restrict__ tmp,
        int* __restrict__ row_start, unsigned short* __restrict__ esrc,
        const unsigned* __restrict__ htb32,
        const float* __restrict__ att_src, const float* __restrict__ att_dst,
        float* __restrict__ a_s, float* __restrict__ a_d,
        int N, int TOT, int nb) {
    __shared__ int sh[256];
    __shared__ int cnt[BUCK];
    __shared__ int cur[BUCK];

    if (blockIdx.x < nb) {
        // ---- fine_scatter path ----
        const int b = blockIdx.x;
        const int t = threadIdx.x;
        scan_btotal(btotal, sh, nb, t);
        const int base = sh[b] - btotal[b];   // exclusive prefix of bucket b
        const int end  = sh[b];
        __syncthreads();

        cnt[t] = 0;
        cnt[t + 256] = 0;
        __syncthreads();
        for (int j = base + t; j < end; j += 256)
            atomicAdd(&cnt[(tmp[j] >> 16) & 511], 1);
        __syncthreads();

        // exclusive scan over 512 entries (2 per thread)
        const int v0 = cnt[2 * t], v1 = cnt[2 * t + 1];
        const int s = v0 + v1;
        sh[t] = s;
        __syncthreads();
        for (int off = 1; off < 256; off <<= 1) {
            int x = (t >= off) ? sh[t - off] : 0;
            __syncthreads();
            sh[t] += x;
            __syncthreads();
        }
        const int excl = sh[t] - s;
        cnt[2 * t]     = excl;
        cnt[2 * t + 1] = excl + v0;
        cur[2 * t]     = excl;
        cur[2 * t + 1] = excl + v0;
        {
            int g = b * BUCK + 2 * t;
            if (g < N)     row_start[g]     = base + excl;
            if (g + 1 < N) row_start[g + 1] = base + excl + v0;
        }
        if (b == 0 && t == 0) row_start[N] = TOT;
        __syncthreads();

        for (int j = base + t; j < end; j += 256) {
            const unsigned e = tmp[j];
            const int pos = base + atomicAdd(&cur[(e >> 16) & 511], 1);
            esrc[pos] = (unsigned short)(e & 0xffffu);
        }
        return;
    }

    // ---- node_logits path ----
    int t = (blockIdx.x - nb) * 256 + threadIdx.x;
    if (t >= N * NH) return;
    const int n  = t >> 2;
    const int hh = t & 3;
    const unsigned* p = htb32 + (size_t)n * (HC / 2) + hh * (CH / 2);
    const float* ps = att_src + hh * CH;
    const float* pd = att_dst + hh * CH;
    float s = 0.f, d = 0.f;
#pragma unroll
    for (int i = 0; i < CH / 2; i += 2) {
        uint2 u = *(const uint2*)(p + i);
        float4 as = *(const float4*)(ps + 2 * i);
        float4 ad = *(const float4*)(pd + 2 * i);
        float v0 = bfu_lo(u.x), v1 = bfu_hi(u.x);
        float v2 = bfu_lo(u.y), v3 = bfu_hi(u.y);
        s += v0 * as.x + v1 * as.y + v2 * as.z + v3 * as.w;
        d += v0 * ad.x + v1 * ad.y + v2 * ad.z + v3 * ad.w;
    }
    a_s[t] = s;
    a_d[t] = d;
}

// ---------------------------------------------------------------------------
// K4: FUSED softmax + aggregation, one wave per dst node (r26 proven:
// inline per-head denominator, no cross-lane reduction).
// ---------------------------------------------------------------------------
__global__ __launch_bounds__(256) void aggregate_fused(
        const int* __restrict__ row_start,
        const unsigned short* __restrict__ esrc,
        const float4* __restrict__ a_s4, const float4* __restrict__ a_d4,
        const unsigned* __restrict__ htb32, const float* __restrict__ bias,
        float* __restrict__ out, int N) {
    __shared__ float exl[4][64 * 4];   // per-wave: 64 edges x 4 heads
    const int wave = threadIdx.x >> 6;
    const int n = blockIdx.x * 4 + wave;
    if (n >= N) return;
    const int lane = threadIdx.x & 63;
    const int hh   = lane >> 4;
    const int c2   = lane * 2;
    const int rs = row_start[n], re = row_start[n + 1];
    const float4 ad = a_d4[n];
    float* exw = exl[wave];

    float ax0 = 0.f, ay0 = 0.f, ax1 = 0.f, ay1 = 0.f;
    float ax2 = 0.f, ay2 = 0.f, ax3 = 0.f, ay3 = 0.f;
    float es0 = 0.f, es1 = 0.f, es2 = 0.f, es3 = 0.f;

    for (int c = rs; c < re; c += 64) {
        const int nc = (re - c < 64) ? (re - c) : 64;
        // phase 1: one lane per edge
        if (lane < nc) {
            const int s = esrc[c + lane];
            const float4 as = a_s4[s];
            const float rx = sig_exp(as.x + ad.x);
            const float ry = sig_exp(as.y + ad.y);
            const float rz = sig_exp(as.z + ad.z);
            const float rw = sig_exp(as.w + ad.w);
            *(float4*)&exw[lane * 4] = make_float4(rx, ry, rz, rw);
        }
        // phase 2: 8-edge unroll (8 gathers in flight), 4 accumulator pairs
        int j = 0;
        for (; j + 7 < nc; j += 8) {
            const int s0 = esrc[c + j],     s1 = esrc[c + j + 1];
            const int s2 = esrc[c + j + 2], s3 = esrc[c + j + 3];
            const int s4 = esrc[c + j + 4], s5 = esrc[c + j + 5];
            const int s6 = esrc[c + j + 6], s7 = esrc[c + j + 7];
            const unsigned u0 = htb32[(size_t)s0 * (HC / 2) + lane];
            const unsigned u1 = htb32[(size_t)s1 * (HC / 2) + lane];
            const unsigned u2 = htb32[(size_t)s2 * (HC / 2) + lane];
            const unsigned u3 = htb32[(size_t)s3 * (HC / 2) + lane];
            const unsigned u4 = htb32[(size_t)s4 * (HC / 2) + lane];
            const unsigned u5 = htb32[(size_t)s5 * (HC / 2) + lane];
            const unsigned u6 = htb32[(size_t)s6 * (HC / 2) + lane];
            const unsigned u7 = htb32[(size_t)s7 * (HC / 2) + lane];
            const float e0 = exw[(j)     * 4 + hh];
            const float e1 = exw[(j + 1) * 4 + hh];
            const float e2 = exw[(j + 2) * 4 + hh];
            const float e3 = exw[(j + 3) * 4 + hh];
            const float e4 = exw[(j + 4) * 4 + hh];
            const float e5 = exw[(j + 5) * 4 + hh];
            const float e6 = exw[(j + 6) * 4 + hh];
            const float e7 = exw[(j + 7) * 4 + hh];
            ax0 += e0 * bfu_lo(u0);  ay0 += e0 * bfu_hi(u0);  es0 += e0;
            ax1 += e1 * bfu_lo(u1);  ay1 += e1 * bfu_hi(u1);  es1 += e1;
            ax2 += e2 * bfu_lo(u2);  ay2 += e2 * bfu_hi(u2);  es2 += e2;
            ax3 += e3 * bfu_lo(u3);  ay3 += e3 * bfu_hi(u3);  es3 += e3;
            ax0 += e4 * bfu_lo(u4);  ay0 += e4 * bfu_hi(u4);  es0 += e4;
            ax1 += e5 * bfu_lo(u5);  ay1 += e5 * bfu_hi(u5);  es1 += e5;
            ax2 += e6 * bfu_lo(u6);  ay2 += e6 * bfu_hi(u6);  es2 += e6;
            ax3 += e7 * bfu_lo(u7);  ay3 += e7 * bfu_hi(u7);  es3 += e7;
        }
        for (; j + 3 < nc; j += 4) {
            const int s0 = esrc[c + j],     s1 = esrc[c + j + 1];
            const int s2 = esrc[c + j + 2], s3 = esrc[c + j + 3];
            const unsigned u0 = htb32[(size_t)s0 * (HC / 2) + lane];
            const unsigned u1 = htb32[(size_t)s1 * (HC / 2) + lane];
            const unsigned u2 = htb32[(size_t)s2 * (HC / 2) + lane];
            const unsigned u3 = htb32[(size_t)s3 * (HC / 2) + lane];
            const float e0 = exw[(j)     * 4 + hh];
            const float e1 = exw[(j + 1) * 4 + hh];
            const float e2 = exw[(j + 2) * 4 + hh];
            const float e3 = exw[(j + 3) * 4 + hh];
            ax0 += e0 * bfu_lo(u0);  ay0 += e0 * bfu_hi(u0);  es0 += e0;
            ax1 += e1 * bfu_lo(u1);  ay1 += e1 * bfu_hi(u1);  es1 += e1;
            ax2 += e2 * bfu_lo(u2);  ay2 += e2 * bfu_hi(u2);  es2 += e2;
            ax3 += e3 * bfu_lo(u3);  ay3 += e3 * bfu_hi(u3);  es3 += e3;
        }
        for (; j < nc; ++j) {
            const int s0 = esrc[c + j];
            const float e0 = exw[j * 4 + hh];
            const unsigned u0 = htb32[(size_t)s0 * (HC / 2) + lane];
            ax0 += e0 * bfu_lo(u0);  ay0 += e0 * bfu_hi(u0);  es0 += e0;
        }
    }

    const float inv = 1.0f / ((es0 + es1) + (es2 + es3));
    float* op = out + (size_t)n * HC + c2;
    op[0] = ((ax0 + ax1) + (ax2 + ax3)) * inv + bias[c2];
    op[1] = ((ay0 + ay1) + (ay2 + ay3)) * inv + bias[c2 + 1];
}

// ---------------------------------------------------------------------------
extern "C" void kernel_launch(void* const* d_in, const int* in_sizes, int n_in,
                              void* d_out, int out_size, void* d_ws, size_t ws_size,
                              hipStream_t stream) {
    const float* h       = (const float*)d_in[0];
    const int*   src     = (const int*)d_in[1];
    const int*   dst     = (const int*)d_in[2];
    const float* W       = (const float*)d_in[3];
    const float* att_src = (const float*)d_in[4];
    const float* att_dst = (const float*)d_in[5];
    const float* bias    = (const float*)d_in[6];
    float*       out     = (float*)d_out;

    const int N = in_sizes[0] / IN_F;   // 50000
    const int E = in_sizes[1];          // 800000
    const int TOT = E + N;
    const int nb = (N + BUCK - 1) / BUCK;        // 98 buckets
    const int chunk = (TOT + NBLK - 1) / NBLK;   // edges per scatter block
    const int g32 = (N + 31) / 32;               // gemm grid (BM=32)
    const int glog = (N * NH + 255) / 256;       // logits grid

    // Workspace layout:
    // htb[N*128] bf16 | a_s[N*4] f32 | a_d[N*4] f32 | row_start[N+1]
    // | btotal[256] | pad | bcount[nb*NBLK] | tmp[TOT] u32 | esrc[TOT] u16
    // | pad | Wt[128*512] bf16
    unsigned short* htb = (unsigned short*)d_ws;
    float* a_s   = (float*)(htb + (size_t)N * HC);
    float* a_d   = a_s + (size_t)N * NH;
    int*   row_start = (int*)(a_d + (size_t)N * NH);
    int*   btotal = row_start + (N + 1);
    size_t off0 = ((size_t)((char*)(btotal + 256) - (char*)d_ws) + 15) & ~(size_t)15;
    int*   bcount = (int*)((char*)d_ws + off0);
    unsigned* tmp = (unsigned*)(bcount + (size_t)nb * NBLK);
    unsigned short* esrc = (unsigned short*)(tmp + TOT);
    size_t off2 = ((size_t)((char*)(esrc + TOT) - (char*)d_ws) + 15) & ~(size_t)15;
    unsigned short* Wt = (unsigned short*)((char*)d_ws + off2);

    // K1: bucket histogram ∥ W prep
    hist_prep<<<NBLK + 256, 256, 0, stream>>>(dst, bcount, W, Wt,
                                              E, N, chunk, nb);
    // K2a: per-bucket block scan
    block_scan<<<nb, 256, 0, stream>>>(bcount, btotal, nb);
    // K2: bucket scatter (LDS sort) ∥ GEMM
    scatter_gemm<<<NBLK + g32, 256, 0, stream>>>(src, dst, bcount, btotal, tmp,
                                                 h, Wt, htb, E, N, chunk, nb);
    // K3: fine scatter ∥ node logits
    fine_logits<<<nb + glog, 256, 0, stream>>>(btotal, tmp, row_start, esrc,
                                               (const unsigned*)htb,
                                               att_src, att_dst, a_s, a_d,
                                               N, TOT, nb);
    // K4: fused softmax + aggregation
    aggregate_fused<<<(N + 3) / 4, 256, 0, stream>>>(row_start, esrc,
                                                     (const float4*)a_s,
                                                     (const float4*)a_d,
                                                     (const unsigned*)htb,
                                                     bias, out, N);
}

// Round 30
// 100.499 us; speedup vs baseline: 1.0803x; 1.0803x over previous
//
#include <hip/hip_runtime.h>
#include <hip/hip_bf16.h>
#include <math.h>

// Problem constants (fixed by reference): IN=512, H=4, C=32, H*C=128.
constexpr int IN_F = 512;
constexpr int NH   = 4;
constexpr int CH   = 32;
constexpr int HC   = 128;   // NH*CH
constexpr int BUCK = 256;   // dst nodes per bucket (CSR-contiguous)
constexpr int NBLK = 512;   // scatter blocks (edge chunks)
constexpr int SCH  = 2048;  // scatter sub-chunk (LDS sort granularity)

typedef short  short8 __attribute__((ext_vector_type(8)));
typedef float  f32x4  __attribute__((ext_vector_type(4)));

typedef __attribute__((address_space(3))) void as3_void;
typedef __attribute__((address_space(1))) void as1_void;
#define GLOAD_LDS16(g, l) \
    __builtin_amdgcn_global_load_lds((const as1_void*)(g), (as3_void*)(l), 16, 0, 0)

__device__ __forceinline__ unsigned short f2bf(float f) {
    unsigned u = __float_as_uint(f);
    unsigned r = (u + 0x7fff + ((u >> 16) & 1)) >> 16;   // RNE
    return (unsigned short)r;
}
__device__ __forceinline__ float bfu_lo(unsigned u) {
    return __uint_as_float(u << 16);
}
__device__ __forceinline__ float bfu_hi(unsigned u) {
    return __uint_as_float(u & 0xffff0000u);
}
__device__ __forceinline__ float sig_exp(float x) {
    return __expf(1.0f / (1.0f + __expf(-x)));
}

// ---------------------------------------------------------------------------
// LDS fragment readers.
// ---------------------------------------------------------------------------
__device__ __forceinline__ short8 frag_read(const char* tile, int row, int kb) {
    const int sw = (row & 7) << 4;
    const int b0 = row * 128 + ((kb)      ^ sw);
    const int b1 = row * 128 + ((kb + 32) ^ sw);
    ushort4 lo = *(const ushort4*)(tile + b0);
    ushort4 hi = *(const ushort4*)(tile + b1);
    short8 f;
    f[0] = (short)lo.x; f[1] = (short)lo.y; f[2] = (short)lo.z; f[3] = (short)lo.w;
    f[4] = (short)hi.x; f[5] = (short)hi.y; f[6] = (short)hi.z; f[7] = (short)hi.w;
    return f;
}

__device__ __forceinline__ short8 frag_read_a(const char* tile, int row, int jb) {
    const int sw = row & 7;
    const float4 lo = *(const float4*)(tile + row * 256 + (((jb)     ^ sw) << 4));
    const float4 hi = *(const float4*)(tile + row * 256 + (((jb + 4) ^ sw) << 4));
    __hip_bfloat162 p0 = __float22bfloat162_rn(float2{lo.x, lo.y});
    __hip_bfloat162 p1 = __float22bfloat162_rn(float2{lo.z, lo.w});
    __hip_bfloat162 p2 = __float22bfloat162_rn(float2{hi.x, hi.y});
    __hip_bfloat162 p3 = __float22bfloat162_rn(float2{hi.z, hi.w});
    unsigned u0 = *(unsigned*)&p0, u1 = *(unsigned*)&p1;
    unsigned u2 = *(unsigned*)&p2, u3 = *(unsigned*)&p3;
    short8 f;
    f[0] = (short)u0; f[1] = (short)(u0 >> 16);
    f[2] = (short)u1; f[3] = (short)(u1 >> 16);
    f[4] = (short)u2; f[5] = (short)(u2 >> 16);
    f[6] = (short)u3; f[7] = (short)(u3 >> 16);
    return f;
}

// ---------------------------------------------------------------------------
// K1: hist (blocks < NBLK) ∥ prep_w (blocks >= NBLK).
// ---------------------------------------------------------------------------
__global__ __launch_bounds__(256) void hist_prep(
        const int* __restrict__ dst, int* __restrict__ bcount,
        const float* __restrict__ W, unsigned short* __restrict__ Wt,
        int E, int N, int chunk, int nb) {
    __shared__ int lh[256];
    if (blockIdx.x < NBLK) {
        const int t = threadIdx.x;
        const int b = blockIdx.x;
        lh[t] = 0;
        __syncthreads();
        const int T = E + N;
        const int lo = b * chunk;
        const int hi = (lo + chunk < T) ? lo + chunk : T;
        for (int e = lo + t; e < hi; e += 256) {
            const int d = (e < E) ? dst[e] : (e - E);
            atomicAdd(&lh[d >> 8], 1);
        }
        __syncthreads();
        if (t < nb) bcount[t * NBLK + b] = lh[t];   // bucket-major
    } else {
        const int t = (blockIdx.x - NBLK) * 256 + threadIdx.x;
        if (t < IN_F * HC) {
            const int k = t >> 7, n = t & 127;
            Wt[(size_t)n * IN_F + k] = f2bf(W[t]);
        }
    }
}

// ---------------------------------------------------------------------------
// Pass 2: per bucket, exclusive scan over NBLK block counts (in place).
// ---------------------------------------------------------------------------
__global__ __launch_bounds__(256) void block_scan(
        int* __restrict__ bcount, int* __restrict__ btotal, int nb) {
    __shared__ int sh[256];
    const int b = blockIdx.x;
    const int t = threadIdx.x;
    const int i0 = b * NBLK + 2 * t;
    const int v0 = bcount[i0], v1 = bcount[i0 + 1];
    const int s = v0 + v1;
    sh[t] = s;
    __syncthreads();
    for (int off = 1; off < 256; off <<= 1) {
        int x = (t >= off) ? sh[t - off] : 0;
        __syncthreads();
        sh[t] += x;
        __syncthreads();
    }
    const int excl = sh[t] - s;
    bcount[i0]     = excl;
    bcount[i0 + 1] = excl + v0;
    if (t == 255) btotal[b] = sh[255];
}

// In-LDS exclusive scan of btotal (inclusive result left in sh).
__device__ __forceinline__ void scan_btotal(const int* __restrict__ btotal,
                                            int* sh, int nb, int t) {
    const int v = (t < nb) ? btotal[t] : 0;
    sh[t] = v;
    __syncthreads();
    for (int off = 1; off < 256; off <<= 1) {
        int x = (t >= off) ? sh[t - off] : 0;
        __syncthreads();
        sh[t] += x;
        __syncthreads();
    }
}

// ---------------------------------------------------------------------------
// K2: scatter (blocks < NBLK, block-local LDS counting sort -> coalesced
// emit) ∥ gemm_f32a (blocks >= NBLK, BM=32). LDS union: 24K tiles / sort bufs.
// ---------------------------------------------------------------------------
__global__ __launch_bounds__(256) void scatter_gemm(
        const int* __restrict__ src, const int* __restrict__ dst,
        const int* __restrict__ bcount, const int* __restrict__ btotal,
        unsigned* __restrict__ tmp,
        const float* __restrict__ A, const unsigned short* __restrict__ Wt,
        unsigned short* __restrict__ C16,
        int E, int N, int chunk, int nb) {
    __shared__ __align__(16) char smem[24576];
    __shared__ int sh[256];
    __shared__ int cur[256];

    if (blockIdx.x < NBLK) {
        // ---- scatter path: block-local counting sort, coalesced emit ----
        unsigned* eload  = (unsigned*)smem;            // [SCH]
        unsigned* sorted = (unsigned*)(smem + 8192);   // [SCH]
        int* lhist = (int*)(smem + 16384);             // [256]
        int* lexcl = (int*)(smem + 16384 + 1024);      // [256]
        int* lcur  = (int*)(smem + 16384 + 2048);      // [256]

        const int t = threadIdx.x;
        const int b = blockIdx.x;
        scan_btotal(btotal, sh, nb, t);
        // per-bucket global write base for this block
        cur[t] = (t < nb) ? (sh[t] - btotal[t]) + bcount[t * NBLK + b] : 0;
        __syncthreads();

        const int T = E + N;
        const int lo0 = b * chunk;
        const int hi0 = (lo0 + chunk < T) ? lo0 + chunk : T;
        for (int base_e = lo0; base_e < hi0; base_e += SCH) {
            const int cnt_e = (hi0 - base_e < SCH) ? (hi0 - base_e) : SCH;
            // load + pack: bucket<<24 | dloc<<16 | src
            for (int i = t; i < cnt_e; i += 256) {
                const int e = base_e + i;
                const int s = (e < E) ? src[e] : (e - E);
                const int d = (e < E) ? dst[e] : (e - E);
                eload[i] = (unsigned)s | ((unsigned)(d & 255) << 16)
                                       | ((unsigned)(d >> 8) << 24);
            }
            lhist[t] = 0;
            __syncthreads();
            for (int i = t; i < cnt_e; i += 256)
                atomicAdd(&lhist[eload[i] >> 24], 1);
            __syncthreads();
            // exclusive scan of lhist
            const int v = lhist[t];
            for (int off = 1; off < 256; off <<= 1) {
                int x = (t >= off) ? lhist[t - off] : 0;
                __syncthreads();
                lhist[t] += x;
                __syncthreads();
            }
            const int excl = lhist[t] - v;
            lexcl[t] = excl;
            lcur[t]  = excl;
            __syncthreads();
            // sort into LDS by bucket
            for (int i = t; i < cnt_e; i += 256) {
                const unsigned ev = eload[i];
                const int p = atomicAdd(&lcur[ev >> 24], 1);
                sorted[p] = ev;
            }
            __syncthreads();
            // emit: consecutive i in a bucket -> consecutive global pos
            for (int i = t; i < cnt_e; i += 256) {
                const unsigned ev = sorted[i];
                const int bk = ev >> 24;
                tmp[cur[bk] + (i - lexcl[bk])] = ev & 0x00ffffffu;
            }
            __syncthreads();
            // advance per-bucket base by this sub-chunk's counts
            if (t < nb) cur[t] += lcur[t] - lexcl[t];
            __syncthreads();
        }
        return;
    }

    // ---- gemm path (BM=32) ----
    char* As = smem;           // 8 KB (f32 tile, 32 rows)
    char* Bs = smem + 8192;    // 16 KB (bf16 tile)

    const int tid  = threadIdx.x;
    const int lane = tid & 63;
    const int wave = tid >> 6;
    const int wr  = wave & 1;
    const int wcq = wave >> 1;
    const int brow = (blockIdx.x - NBLK) * 32;
    const int lr = lane & 15;
    const int lg = lane >> 4;

    f32x4 acc[4];
#pragma unroll
    for (int j = 0; j < 4; ++j)
        acc[j] = f32x4{0.f, 0.f, 0.f, 0.f};

    for (int kc = 0; kc < IN_F; kc += 64) {
        __syncthreads();
#pragma unroll
        for (int p = 0; p < 2; ++p) {
            const int c = tid + 256 * p;
            const int r = c >> 4, j = c & 15;
            int gr = brow + r;
            if (gr >= N) gr = 0;
            const float* srcp = A + (size_t)gr * IN_F + kc + ((j ^ (r & 7)) << 2);
            GLOAD_LDS16(srcp, As + wave * 1024 + p * 4096);
        }
#pragma unroll
        for (int p = 0; p < 4; ++p) {
            const int c = tid + 256 * p;
            const int n = c >> 3, j = c & 7;
            const unsigned short* srcp = Wt + (size_t)n * IN_F + kc
                                         + ((j ^ (n & 7)) << 3);
            GLOAD_LDS16(srcp, Bs + wave * 1024 + p * 4096);
        }
        __syncthreads();

#pragma unroll
        for (int ks = 0; ks < 2; ++ks) {
            const int jb = ks * 8 + lg;
            const int kb = ks * 64 + 8 * lg;
            short8 af = frag_read_a(As, wr * 16 + lr, jb);
            short8 bf[4];
#pragma unroll
            for (int ni = 0; ni < 4; ++ni)
                bf[ni] = frag_read(Bs, wcq * 64 + ni * 16 + lr, kb);
#pragma unroll
            for (int ni = 0; ni < 4; ++ni)
                acc[ni] = __builtin_amdgcn_mfma_f32_16x16x32_bf16(
                    af, bf[ni], acc[ni], 0, 0, 0);
        }
    }

    const int r0 = brow + wr * 16 + 4 * lg;
#pragma unroll
    for (int ni = 0; ni < 4; ++ni) {
        const int c0 = wcq * 64 + ni * 16 + lr;
#pragma unroll
        for (int j = 0; j < 4; ++j) {
            const int r = r0 + j;
            if (r < N) C16[(size_t)r * HC + c0] = f2bf(acc[ni][j]);
        }
    }
}

// ---------------------------------------------------------------------------
// K3: fine_scatter (blocks < nb) ∥ node_logits (blocks >= nb).
// ---------------------------------------------------------------------------
__global__ __launch_bounds__(256) void fine_logits(
        const int* __restrict__ btotal, const unsigned* __restrict__ tmp,
        int* __restrict__ row_start, unsigned short* __restrict__ esrc,
        const unsigned* __restrict__ htb32,
        const float* __restrict__ att_src, const float* __restrict__ att_dst,
        float* __restrict__ a_s, float* __restrict__ a_d,
        int N, int TOT, int nb) {
    __shared__ int sh[256];
    __shared__ int cnt[256];
    __shared__ int cur[256];

    if (blockIdx.x < nb) {
        // ---- fine_scatter path ----
        const int b = blockIdx.x;
        const int t = threadIdx.x;
        scan_btotal(btotal, sh, nb, t);
        const int base = sh[b] - btotal[b];   // exclusive prefix of bucket b
        const int end  = sh[b];
        __syncthreads();

        cnt[t] = 0;
        __syncthreads();
        for (int j = base + t; j < end; j += 256)
            atomicAdd(&cnt[tmp[j] >> 16], 1);
        __syncthreads();

        const int v = cnt[t];
        for (int off = 1; off < 256; off <<= 1) {
            int x = (t >= off) ? cnt[t - off] : 0;
            __syncthreads();
            cnt[t] += x;
            __syncthreads();
        }
        const int excl = cnt[t] - v;
        cur[t] = excl;
        const int g = b * BUCK + t;
        if (g < N) row_start[g] = base + excl;
        if (b == 0 && t == 0) row_start[N] = TOT;
        __syncthreads();

        for (int j = base + t; j < end; j += 256) {
            const unsigned e = tmp[j];
            const int pos = base + atomicAdd(&cur[e >> 16], 1);
            esrc[pos] = (unsigned short)(e & 0xffffu);
        }
        return;
    }

    // ---- node_logits path ----
    int t = (blockIdx.x - nb) * 256 + threadIdx.x;
    if (t >= N * NH) return;
    const int n  = t >> 2;
    const int hh = t & 3;
    const unsigned* p = htb32 + (size_t)n * (HC / 2) + hh * (CH / 2);
    const float* ps = att_src + hh * CH;
    const float* pd = att_dst + hh * CH;
    float s = 0.f, d = 0.f;
#pragma unroll
    for (int i = 0; i < CH / 2; i += 2) {
        uint2 u = *(const uint2*)(p + i);
        float4 as = *(const float4*)(ps + 2 * i);
        float4 ad = *(const float4*)(pd + 2 * i);
        float v0 = bfu_lo(u.x), v1 = bfu_hi(u.x);
        float v2 = bfu_lo(u.y), v3 = bfu_hi(u.y);
        s += v0 * as.x + v1 * as.y + v2 * as.z + v3 * as.w;
        d += v0 * ad.x + v1 * ad.y + v2 * ad.z + v3 * ad.w;
    }
    a_s[t] = s;
    a_d[t] = d;
}

// ---------------------------------------------------------------------------
// K4: FUSED softmax + aggregation, one wave per dst node.
// Phase 1: one lane per edge computes ex[h] into per-wave LDS (1x trans).
// Phase 2: 8-edge-unrolled FMA gather; per-head denominator accumulated
// INLINE from the broadcast e values (no cross-lane shfl tail at all).
// ---------------------------------------------------------------------------
__global__ __launch_bounds__(256) void aggregate_fused(
        const int* __restrict__ row_start,
        const unsigned short* __restrict__ esrc,
        const float4* __restrict__ a_s4, const float4* __restrict__ a_d4,
        const unsigned* __restrict__ htb32, const float* __restrict__ bias,
        float* __restrict__ out, int N) {
    __shared__ float exl[4][64 * 4];   // per-wave: 64 edges x 4 heads
    const int wave = threadIdx.x >> 6;
    const int n = blockIdx.x * 4 + wave;
    if (n >= N) return;
    const int lane = threadIdx.x & 63;
    const int hh   = lane >> 4;
    const int c2   = lane * 2;
    const int rs = row_start[n], re = row_start[n + 1];
    const float4 ad = a_d4[n];
    float* exw = exl[wave];

    float ax0 = 0.f, ay0 = 0.f, ax1 = 0.f, ay1 = 0.f;
    float ax2 = 0.f, ay2 = 0.f, ax3 = 0.f, ay3 = 0.f;
    float es0 = 0.f, es1 = 0.f, es2 = 0.f, es3 = 0.f;

    for (int c = rs; c < re; c += 64) {
        const int nc = (re - c < 64) ? (re - c) : 64;
        // phase 1: one lane per edge
        if (lane < nc) {
            const int s = esrc[c + lane];
            const float4 as = a_s4[s];
            const float rx = sig_exp(as.x + ad.x);
            const float ry = sig_exp(as.y + ad.y);
            const float rz = sig_exp(as.z + ad.z);
            const float rw = sig_exp(as.w + ad.w);
            *(float4*)&exw[lane * 4] = make_float4(rx, ry, rz, rw);
        }
        // phase 2: 8-edge unroll (8 gathers in flight), 4 accumulator pairs
        int j = 0;
        for (; j + 7 < nc; j += 8) {
            const int s0 = esrc[c + j],     s1 = esrc[c + j + 1];
            const int s2 = esrc[c + j + 2], s3 = esrc[c + j + 3];
            const int s4 = esrc[c + j + 4], s5 = esrc[c + j + 5];
            const int s6 = esrc[c + j + 6], s7 = esrc[c + j + 7];
            const unsigned u0 = htb32[(size_t)s0 * (HC / 2) + lane];
            const unsigned u1 = htb32[(size_t)s1 * (HC / 2) + lane];
            const unsigned u2 = htb32[(size_t)s2 * (HC / 2) + lane];
            const unsigned u3 = htb32[(size_t)s3 * (HC / 2) + lane];
            const unsigned u4 = htb32[(size_t)s4 * (HC / 2) + lane];
            const unsigned u5 = htb32[(size_t)s5 * (HC / 2) + lane];
            const unsigned u6 = htb32[(size_t)s6 * (HC / 2) + lane];
            const unsigned u7 = htb32[(size_t)s7 * (HC / 2) + lane];
            const float e0 = exw[(j)     * 4 + hh];
            const float e1 = exw[(j + 1) * 4 + hh];
            const float e2 = exw[(j + 2) * 4 + hh];
            const float e3 = exw[(j + 3) * 4 + hh];
            const float e4 = exw[(j + 4) * 4 + hh];
            const float e5 = exw[(j + 5) * 4 + hh];
            const float e6 = exw[(j + 6) * 4 + hh];
            const float e7 = exw[(j + 7) * 4 + hh];
            ax0 += e0 * bfu_lo(u0);  ay0 += e0 * bfu_hi(u0);  es0 += e0;
            ax1 += e1 * bfu_lo(u1);  ay1 += e1 * bfu_hi(u1);  es1 += e1;
            ax2 += e2 * bfu_lo(u2);  ay2 += e2 * bfu_hi(u2);  es2 += e2;
            ax3 += e3 * bfu_lo(u3);  ay3 += e3 * bfu_hi(u3);  es3 += e3;
            ax0 += e4 * bfu_lo(u4);  ay0 += e4 * bfu_hi(u4);  es0 += e4;
            ax1 += e5 * bfu_lo(u5);  ay1 += e5 * bfu_hi(u5);  es1 += e5;
            ax2 += e6 * bfu_lo(u6);  ay2 += e6 * bfu_hi(u6);  es2 += e6;
            ax3 += e7 * bfu_lo(u7);  ay3 += e7 * bfu_hi(u7);  es3 += e7;
        }
        for (; j + 3 < nc; j += 4) {
            const int s0 = esrc[c + j],     s1 = esrc[c + j + 1];
            const int s2 = esrc[c + j + 2], s3 = esrc[c + j + 3];
            const unsigned u0 = htb32[(size_t)s0 * (HC / 2) + lane];
            const unsigned u1 = htb32[(size_t)s1 * (HC / 2) + lane];
            const unsigned u2 = htb32[(size_t)s2 * (HC / 2) + lane];
            const unsigned u3 = htb32[(size_t)s3 * (HC / 2) + lane];
            const float e0 = exw[(j)     * 4 + hh];
            const float e1 = exw[(j + 1) * 4 + hh];
            const float e2 = exw[(j + 2) * 4 + hh];
            const float e3 = exw[(j + 3) * 4 + hh];
            ax0 += e0 * bfu_lo(u0);  ay0 += e0 * bfu_hi(u0);  es0 += e0;
            ax1 += e1 * bfu_lo(u1);  ay1 += e1 * bfu_hi(u1);  es1 += e1;
            ax2 += e2 * bfu_lo(u2);  ay2 += e2 * bfu_hi(u2);  es2 += e2;
            ax3 += e3 * bfu_lo(u3);  ay3 += e3 * bfu_hi(u3);  es3 += e3;
        }
        for (; j < nc; ++j) {
            const int s0 = esrc[c + j];
            const float e0 = exw[j * 4 + hh];
            const unsigned u0 = htb32[(size_t)s0 * (HC / 2) + lane];
            ax0 += e0 * bfu_lo(u0);  ay0 += e0 * bfu_hi(u0);  es0 += e0;
        }
    }

    const float inv = 1.0f / ((es0 + es1) + (es2 + es3));
    float* op = out + (size_t)n * HC + c2;
    op[0] = ((ax0 + ax1) + (ax2 + ax3)) * inv + bias[c2];
    op[1] = ((ay0 + ay1) + (ay2 + ay3)) * inv + bias[c2 + 1];
}

// ---------------------------------------------------------------------------
extern "C" void kernel_launch(void* const* d_in, const int* in_sizes, int n_in,
                              void* d_out, int out_size, void* d_ws, size_t ws_size,
                              hipStream_t stream) {
    const float* h       = (const float*)d_in[0];
    const int*   src     = (const int*)d_in[1];
    const int*   dst     = (const int*)d_in[2];
    const float* W       = (const float*)d_in[3];
    const float* att_src = (const float*)d_in[4];
    const float* att_dst = (const float*)d_in[5];
    const float* bias    = (const float*)d_in[6];
    float*       out     = (float*)d_out;

    const int N = in_sizes[0] / IN_F;   // 50000
    const int E = in_sizes[1];          // 800000
    const int TOT = E + N;
    const int nb = (N + BUCK - 1) / BUCK;        // 196 buckets
    const int chunk = (TOT + NBLK - 1) / NBLK;   // edges per scatter block
    const int g32 = (N + 31) / 32;               // gemm grid (BM=32)
    const int glog = (N * NH + 255) / 256;       // logits grid

    // Workspace layout:
    // htb[N*128] bf16 | a_s[N*4] f32 | a_d[N*4] f32 | row_start[N+1]
    // | btotal[256] | pad | bcount[nb*NBLK] | tmp[TOT] u32 | esrc[TOT] u16
    // | pad | Wt[128*512] bf16
    unsigned short* htb = (unsigned short*)d_ws;
    float* a_s   = (float*)(htb + (size_t)N * HC);
    float* a_d   = a_s + (size_t)N * NH;
    int*   row_start = (int*)(a_d + (size_t)N * NH);
    int*   btotal = row_start + (N + 1);
    size_t off0 = ((size_t)((char*)(btotal + 256) - (char*)d_ws) + 15) & ~(size_t)15;
    int*   bcount = (int*)((char*)d_ws + off0);
    unsigned* tmp = (unsigned*)(bcount + (size_t)nb * NBLK);
    unsigned short* esrc = (unsigned short*)(tmp + TOT);
    size_t off2 = ((size_t)((char*)(esrc + TOT) - (char*)d_ws) + 15) & ~(size_t)15;
    unsigned short* Wt = (unsigned short*)((char*)d_ws + off2);

    // K1: bucket histogram ∥ W prep
    hist_prep<<<NBLK + 256, 256, 0, stream>>>(dst, bcount, W, Wt,
                                              E, N, chunk, nb);
    // K2a: per-bucket block scan
    block_scan<<<nb, 256, 0, stream>>>(bcount, btotal, nb);
    // K2: bucket scatter (LDS sort) ∥ GEMM
    scatter_gemm<<<NBLK + g32, 256, 0, stream>>>(src, dst, bcount, btotal, tmp,
                                                 h, Wt, htb, E, N, chunk, nb);
    // K3: fine scatter ∥ node logits
    fine_logits<<<nb + glog, 256, 0, stream>>>(btotal, tmp, row_start, esrc,
                                               (const unsigned*)htb,
                                               att_src, att_dst, a_s, a_d,
                                               N, TOT, nb);
    // K4: fused softmax + aggregation
    aggregate_fused<<<(N + 3) / 4, 256, 0, stream>>>(row_start, esrc,
                                                     (const float4*)a_s,
                                                     (const float4*)a_d,
                                                     (const unsigned*)htb,
                                                     bias, out, N);
}